// Round 18
// baseline (258.021 us; speedup 1.0000x reference)
//
#include <hip/hip_runtime.h>

#define NN 20000

typedef _Float16 half8 __attribute__((ext_vector_type(8)));
typedef _Float16 half2v __attribute__((ext_vector_type(2)));
typedef float floatx16 __attribute__((ext_vector_type(16)));

#define MFMA32(a, b, c) __builtin_amdgcn_mfma_f32_32x32x16_f16((a), (b), (c), 0, 0, 0)
#define LD8(p) (*(const half8*)(p))

// ---------------- closed-form cubic B-spline basis (knots -2.5+0.5k) ----------------
__device__ __forceinline__ void bspline7_fast(float x, float b[7]) {
  float u = (x + 2.5f) * 2.0f;
  float cf = floorf(u);
  int c = (int)cf;
  float t = u - cf;
  float omt = 1.0f - t;
  float t2 = t * t, t3 = t2 * t;
  float w0 = omt * omt * omt * (1.0f / 6.0f);
  float w1 = (3.0f * t3 - 6.0f * t2 + 4.0f) * (1.0f / 6.0f);
  float w2 = (-3.0f * t3 + 3.0f * t2 + 3.0f * t + 1.0f) * (1.0f / 6.0f);
  float w3 = t3 * (1.0f / 6.0f);
  bool valid = (c >= 0) && (c <= 9);
#pragma unroll
  for (int i = 0; i < 7; ++i) {
    int d = c - i;
    float w = (d == 0) ? w3 : (d == 1) ? w2 : (d == 2) ? w1 : (d == 3) ? w0 : 0.0f;
    b[i] = valid ? w : 0.0f;
  }
}

__device__ __forceinline__ float silu_f(float x) {
  return x * (1.0f / (1.0f + __expf(-x)));
}

__device__ __forceinline__ half8 afrag(float xv) {
  float b[7];
  bspline7_fast(xv, b);
  half8 hv;
  hv[0] = (_Float16)silu_f(xv);
#pragma unroll
  for (int k = 0; k < 7; ++k) hv[k + 1] = (_Float16)b[k];
  return hv;
}

// ---------------- weight packs (32x32x16 B-fragments) + init tail ----------------
__global__ void packw_all(const float* __restrict__ Wb0, const float* __restrict__ Ws0,
                          const float* __restrict__ Wb1, const float* __restrict__ Ws1,
                          const float* __restrict__ WbO, const float* __restrict__ WsO,
                          _Float16* __restrict__ WPA0, _Float16* __restrict__ WPA1,
                          _Float16* __restrict__ WPC, int* __restrict__ degE,
                          float* __restrict__ ssb) {
  int bid = blockIdx.x;
  if (bid < 1536) {
    int s = (bid >= 768) ? 1 : 0;
    int idx = (bid - s * 768) * 256 + threadIdx.x;  // 64*6*64*8 = 196608
    if (idx >= 196608) return;
    const float* Wb = s ? Wb1 : Wb0;
    const float* Wsp = s ? Ws1 : Ws0;
    _Float16* WP = s ? WPA1 : WPA0;
    int j = idx & 7;
    int lane = (idx >> 3) & 63;
    int u = idx >> 9;  // ks*6 + cb32
    int cb = u % 6, ks = u / 6;
    int i = ks * 2 + (lane >> 5);
    int o32 = lane & 31;
    float v = 0.0f;
    if (cb < 4) {
      int o = cb * 32 + o32;
      v = (j == 0) ? Wb[(size_t)o * 128 + i] : Wsp[(size_t)o * 896 + i * 7 + (j - 1)];
    } else {
      int o = (cb - 4) * 32 + o32;
      if (o < 40)
        v = (j == 0) ? WbO[(size_t)o * 384 + s * 128 + i]
                     : WsO[(size_t)o * 2688 + s * 896 + i * 7 + (j - 1)];
    }
    WP[idx] = (_Float16)v;
  } else if (bid < 1792) {
    int idx = (bid - 1536) * 256 + threadIdx.x;  // 64*2*64*8 = 65536
    if (idx >= 65536) return;
    int j = idx & 7;
    int lane = (idx >> 3) & 63;
    int u = idx >> 9;  // ks*2 + cb32
    int cb = u & 1, ks = u >> 1;
    int i = ks * 2 + (lane >> 5);
    int o = cb * 32 + (lane & 31);
    float v = 0.0f;
    if (o < 40)
      v = (j == 0) ? WbO[(size_t)o * 384 + 2 * 128 + i]
                   : WsO[(size_t)o * 2688 + 2 * 896 + i * 7 + (j - 1)];
    WPC[idx] = (_Float16)v;
  } else if (bid < 1871) {
    int idx = (bid - 1792) * 256 + threadIdx.x;
    if (idx < NN) degE[idx] = 0;
  } else {
    int t = threadIdx.x;
    ssb[t] = (t < 128) ? 1.0f : 0.0f;  // identity BN for layer 0
  }
}

// ---------------- graph meta ----------------
__global__ void count_deg(const int* __restrict__ dst, int* __restrict__ degE, int E) {
  int e = blockIdx.x * 256 + threadIdx.x;
  if (e < E) atomicAdd(&degE[dst[e]], 1);
}

__global__ void build_meta2(const int* __restrict__ degE, int* __restrict__ rowptr,
                            int* __restrict__ cursor, float* __restrict__ dinv, int n) {
  __shared__ int wsum[16];
  int tid = threadIdx.x, lane = tid & 63, wid = tid >> 6;
  int i0 = tid * 20;
  int d[20];
  int s = 0;
#pragma unroll
  for (int j = 0; j < 20; ++j) {
    int i = i0 + j;
    int v = (i < n) ? degE[i] : 0;
    d[j] = v;
    s += v;
    if (i < n) dinv[i] = rsqrtf((float)(v + 1));  // +1 self loop
  }
  int val = s;
#pragma unroll
  for (int off = 1; off < 64; off <<= 1) {
    int t = __shfl_up(val, off);
    if (lane >= off) val += t;
  }
  if (lane == 63) wsum[wid] = val;
  __syncthreads();
  if (wid == 0) {
    int wv = (lane < 16) ? wsum[lane] : 0;
#pragma unroll
    for (int off = 1; off < 16; off <<= 1) {
      int t = __shfl_up(wv, off);
      if (lane >= off) wv += t;
    }
    if (lane < 16) wsum[lane] = wv;
  }
  __syncthreads();
  int base = (wid ? wsum[wid - 1] : 0) + val - s;
  if (tid == 0) rowptr[0] = 0;
#pragma unroll
  for (int j = 0; j < 20; ++j) {
    int i = i0 + j;
    if (i < n) {
      cursor[i] = base;
      rowptr[i + 1] = base + d[j];
      base += d[j];
    }
  }
}

__global__ void fill_csr(const int* __restrict__ src, const int* __restrict__ dst,
                         int* __restrict__ cursor, int* __restrict__ csr, int E) {
  int e = blockIdx.x * 256 + threadIdx.x;
  if (e < E) {
    int p = atomicAdd(&cursor[dst[e]], 1);
    csr[p] = src[e];
  }
}

// ---------------- KAN GEMM: fused build + MFMA32 + split-K x2 + B register-preload ----------------
// 768 thr = 12 waves: cb = w%6 (32-col block), kh = w/6 (K half, 32 ks each).
__global__ __launch_bounds__(768) void gemmSA(const float* __restrict__ X,
                                              const float* __restrict__ ss,
                                              const _Float16* __restrict__ WP,
                                              const float* __restrict__ dinv,
                                              _Float16* __restrict__ A, float* __restrict__ P) {
  __shared__ _Float16 Fs[32 * 1024];  // 64 KB
  int tid = threadIdx.x;
  int lane = tid & 63, w = tid >> 6;
  int cb = w % 6, kh = w / 6;
  int row0 = blockIdx.x * 32;
  for (int idx = tid; idx < 4096; idx += 768) {
    int r = idx >> 7, i = idx & 127;
    float xv = X[(size_t)(row0 + r) * 128 + i] * ss[i] + ss[128 + i];
    *(half8*)(Fs + ((size_t)r * 128 + (i ^ (r & 7))) * 8) = afrag(xv);
  }
  int r = lane & 31, hi = lane >> 5, rx = r & 7;
  const _Float16* Fr = Fs + (size_t)r * 1024;
  int ks0 = kh * 32;
  const _Float16* Bp = WP + (size_t)ks0 * 3072 + ((size_t)cb * 64 + lane) * 8;
  // preload this wave's whole B-half into registers (32 x 16B = 128 VGPR);
  // loads overlap the build VALU above (issued before the barrier).
  half8 bb[32];
#pragma unroll
  for (int k = 0; k < 32; ++k) bb[k] = LD8(Bp + (size_t)k * 3072);
  asm volatile("" ::: "memory");  // fence: loads may not sink past here
  __syncthreads();

  floatx16 acc = {};
#pragma unroll
  for (int k = 0; k < 32; ++k) {
    half8 a = LD8(Fr + (size_t)((2 * (ks0 + k) + hi) ^ rx) * 8);
    acc = MFMA32(a, bb[k], acc);
  }
  __syncthreads();  // all waves done reading Fs
  float* red = (float*)Fs;
  if (kh == 1) {
#pragma unroll
    for (int q = 0; q < 16; ++q) red[q * 384 + cb * 64 + lane] = acc[q];
  }
  __syncthreads();
  if (kh == 0) {
    int col = lane & 31;
#pragma unroll
    for (int q = 0; q < 16; ++q) {
      float v = acc[q] + red[q * 384 + cb * 64 + lane];
      int rl = (q & 3) + 8 * (q >> 2) + 4 * hi;
      if (cb < 4)
        A[(size_t)(row0 + rl) * 128 + cb * 32 + col] = (_Float16)(v * dinv[row0 + rl]);
      else
        P[(size_t)(row0 + rl) * 64 + (cb - 4) * 32 + col] = v;
    }
  }
}

// output chunk 2: fused build + MFMA32 + split-K x4 + B register-preload (16 x 16B = 64 VGPR)
// 512 thr = 8 waves: cb = w&1, kh = w>>1 (16 ks each).
__global__ __launch_bounds__(512) void gemmSC(const float* __restrict__ X,
                                              const float* __restrict__ ss,
                                              const _Float16* __restrict__ WP,
                                              const float* __restrict__ P0,
                                              const float* __restrict__ P1,
                                              const float* __restrict__ dinv,
                                              _Float16* __restrict__ C) {
  __shared__ _Float16 Fs[32 * 1024];  // 64 KB
  int tid = threadIdx.x;
  int lane = tid & 63, w = tid >> 6;
  int cb = w & 1, kh = w >> 1;
  int row0 = blockIdx.x * 32;
  for (int idx = tid; idx < 4096; idx += 512) {
    int r = idx >> 7, i = idx & 127;
    float xv = X[(size_t)(row0 + r) * 128 + i] * ss[i] + ss[128 + i];
    *(half8*)(Fs + ((size_t)r * 128 + (i ^ (r & 7))) * 8) = afrag(xv);
  }
  int r = lane & 31, hi = lane >> 5, rx = r & 7;
  const _Float16* Fr = Fs + (size_t)r * 1024;
  int ks0 = kh * 16;
  const _Float16* Bp = WP + (size_t)ks0 * 1024 + ((size_t)cb * 64 + lane) * 8;
  half8 bb[16];
#pragma unroll
  for (int k = 0; k < 16; ++k) bb[k] = LD8(Bp + (size_t)k * 1024);
  asm volatile("" ::: "memory");
  __syncthreads();

  floatx16 acc = {};
#pragma unroll
  for (int k = 0; k < 16; ++k) {
    half8 a = LD8(Fr + (size_t)((2 * (ks0 + k) + hi) ^ rx) * 8);
    acc = MFMA32(a, bb[k], acc);
  }
  __syncthreads();  // all waves done reading Fs
  float* red = (float*)Fs;
  if (kh > 0) {
#pragma unroll
    for (int q = 0; q < 16; ++q)
      red[((kh - 1) * 16 + q) * 128 + cb * 64 + lane] = acc[q];
  }
  __syncthreads();
  if (kh == 0) {
    int col = lane & 31;
#pragma unroll
    for (int q = 0; q < 16; ++q) {
      float v = acc[q] + red[q * 128 + cb * 64 + lane] +
                red[(16 + q) * 128 + cb * 64 + lane] + red[(32 + q) * 128 + cb * 64 + lane];
      int rl = (q & 3) + 8 * (q >> 2) + 4 * hi;
      size_t idx = (size_t)(row0 + rl) * 64 + cb * 32 + col;
      C[idx] = (_Float16)((v + P0[idx] + P1[idx]) * dinv[row0 + rl]);
    }
  }
}

// ---------------- aggregation: wave per node, pre-scaled fp16 rows, 4-way ILP ----------------
__global__ __launch_bounds__(256) void aggregate128h(const _Float16* __restrict__ Ah,
                                                     const int* __restrict__ rowptr,
                                                     const int* __restrict__ csr,
                                                     const float* __restrict__ dinv,
                                                     const float* __restrict__ bias,
                                                     float* __restrict__ Y) {
  int wid = threadIdx.x >> 6, lane = threadIdx.x & 63;
  int n = blockIdx.x * 4 + wid;  // grid 5000 -> n < 20000
  float di = dinv[n];
  half2v self = *(const half2v*)(Ah + (size_t)n * 128 + lane * 2);
  float a0 = (float)self[0], a1 = (float)self[1];
  float b0x = 0, b0y = 0, b1x = 0, b1y = 0, b2x = 0, b2y = 0, b3x = 0, b3y = 0;
  int e0 = rowptr[n], m = rowptr[n + 1] - e0;
  int j = 0;
  for (; j + 4 <= m; j += 4) {
    int s0 = csr[e0 + j], s1 = csr[e0 + j + 1], s2 = csr[e0 + j + 2], s3 = csr[e0 + j + 3];
    half2v r0 = *(const half2v*)(Ah + (size_t)s0 * 128 + lane * 2);
    half2v r1 = *(const half2v*)(Ah + (size_t)s1 * 128 + lane * 2);
    half2v r2 = *(const half2v*)(Ah + (size_t)s2 * 128 + lane * 2);
    half2v r3 = *(const half2v*)(Ah + (size_t)s3 * 128 + lane * 2);
    b0x += (float)r0[0]; b0y += (float)r0[1];
    b1x += (float)r1[0]; b1y += (float)r1[1];
    b2x += (float)r2[0]; b2y += (float)r2[1];
    b3x += (float)r3[0]; b3y += (float)r3[1];
  }
  for (; j < m; ++j) {
    int s = csr[e0 + j];
    half2v rr = *(const half2v*)(Ah + (size_t)s * 128 + lane * 2);
    b0x += (float)rr[0]; b0y += (float)rr[1];
  }
  a0 += (b0x + b1x) + (b2x + b3x);
  a1 += (b0y + b1y) + (b2y + b3y);
  float2 outv = {a0 * di + bias[lane * 2], a1 * di + bias[lane * 2 + 1]};
  *(float2*)(Y + (size_t)n * 128 + lane * 2) = outv;
}

__global__ __launch_bounds__(256) void aggregate40h(const _Float16* __restrict__ Ch,
                                                    const int* __restrict__ rowptr,
                                                    const int* __restrict__ csr,
                                                    const float* __restrict__ dinv,
                                                    const float* __restrict__ bias,
                                                    float* __restrict__ out) {
  int wid = threadIdx.x >> 6, lane = threadIdx.x & 63;
  int n = blockIdx.x * 4 + wid;
  float di = dinv[n];
  float a = (float)Ch[(size_t)n * 64 + lane];
  float b0 = 0, b1 = 0, b2 = 0, b3 = 0;
  int e0 = rowptr[n], m = rowptr[n + 1] - e0;
  int j = 0;
  for (; j + 4 <= m; j += 4) {
    int s0 = csr[e0 + j], s1 = csr[e0 + j + 1], s2 = csr[e0 + j + 2], s3 = csr[e0 + j + 3];
    b0 += (float)Ch[(size_t)s0 * 64 + lane];
    b1 += (float)Ch[(size_t)s1 * 64 + lane];
    b2 += (float)Ch[(size_t)s2 * 64 + lane];
    b3 += (float)Ch[(size_t)s3 * 64 + lane];
  }
  for (; j < m; ++j) {
    int s = csr[e0 + j];
    b0 += (float)Ch[(size_t)s * 64 + lane];
  }
  a += (b0 + b1) + (b2 + b3);
  if (lane < 40) out[(size_t)n * 40 + lane] = a * di + bias[lane];
}

// ---------------- batchnorm: 3-stage deterministic tree ----------------
__global__ __launch_bounds__(256) void bn_stats(const float* __restrict__ H,
                                                float* __restrict__ partial) {
  int tid = threadIdx.x;
  int c4 = (tid & 31) * 4;
  int r0 = blockIdx.x * 32 + (tid >> 5) * 4;
  float s0 = 0, s1 = 0, s2 = 0, s3 = 0, q0 = 0, q1 = 0, q2 = 0, q3 = 0;
#pragma unroll
  for (int j = 0; j < 4; ++j) {
    float4 v = *(const float4*)(H + (size_t)(r0 + j) * 128 + c4);
    s0 += v.x; s1 += v.y; s2 += v.z; s3 += v.w;
    q0 += v.x * v.x; q1 += v.y * v.y; q2 += v.z * v.z; q3 += v.w * v.w;
  }
  __shared__ float sh[2][256][4];
  sh[0][tid][0] = s0; sh[0][tid][1] = s1; sh[0][tid][2] = s2; sh[0][tid][3] = s3;
  sh[1][tid][0] = q0; sh[1][tid][1] = q1; sh[1][tid][2] = q2; sh[1][tid][3] = q3;
  __syncthreads();
  if (tid < 32) {
    float a0 = 0, a1 = 0, a2 = 0, a3 = 0, b0 = 0, b1 = 0, b2 = 0, b3 = 0;
#pragma unroll
    for (int g = 0; g < 8; ++g) {
      int u = g * 32 + tid;
      a0 += sh[0][u][0]; a1 += sh[0][u][1]; a2 += sh[0][u][2]; a3 += sh[0][u][3];
      b0 += sh[1][u][0]; b1 += sh[1][u][1]; b2 += sh[1][u][2]; b3 += sh[1][u][3];
    }
    float* p = partial + (size_t)blockIdx.x * 256;
    p[tid * 4 + 0] = a0; p[tid * 4 + 1] = a1; p[tid * 4 + 2] = a2; p[tid * 4 + 3] = a3;
    p[128 + tid * 4 + 0] = b0; p[128 + tid * 4 + 1] = b1;
    p[128 + tid * 4 + 2] = b2; p[128 + tid * 4 + 3] = b3;
  }
}

__global__ __launch_bounds__(256) void bn_reduce(const float* __restrict__ partial,
                                                 float* __restrict__ p2) {
  int tid = threadIdx.x;
  const float* base = partial + (size_t)blockIdx.x * 25 * 256 + tid;
  float a0 = 0, a1 = 0, a2 = 0, a3 = 0, a4 = 0;
#pragma unroll
  for (int j = 0; j < 5; ++j) {
    a0 += base[(j * 5 + 0) * 256];
    a1 += base[(j * 5 + 1) * 256];
    a2 += base[(j * 5 + 2) * 256];
    a3 += base[(j * 5 + 3) * 256];
    a4 += base[(j * 5 + 4) * 256];
  }
  p2[(size_t)blockIdx.x * 256 + tid] = ((a0 + a1) + (a2 + a3)) + a4;
}

__global__ __launch_bounds__(256) void bn_final2(const float* __restrict__ p2,
                                                 const float* __restrict__ gamma,
                                                 const float* __restrict__ beta,
                                                 float* __restrict__ ss) {
  int tid = threadIdx.x;
  double a0 = 0, a1 = 0, a2 = 0, a3 = 0, a4 = 0;
#pragma unroll
  for (int j = 0; j < 5; ++j) {
    a0 += (double)p2[(size_t)(j * 5 + 0) * 256 + tid];
    a1 += (double)p2[(size_t)(j * 5 + 1) * 256 + tid];
    a2 += (double)p2[(size_t)(j * 5 + 2) * 256 + tid];
    a3 += (double)p2[(size_t)(j * 5 + 3) * 256 + tid];
    a4 += (double)p2[(size_t)(j * 5 + 4) * 256 + tid];
  }
  double tot = ((a0 + a1) + (a2 + a3)) + a4;
  __shared__ double sh[256];
  sh[tid] = tot;
  __syncthreads();
  if (tid < 128) {
    double S = sh[tid];
    double Q = sh[128 + tid];
    double mean = S / (double)NN;
    double var = Q / (double)NN - mean * mean;
    float sc = gamma[tid] * rsqrtf((float)var + 1e-5f);
    ss[tid] = sc;
    ss[128 + tid] = beta[tid] - (float)mean * sc;
  }
}

// ---------------- launch ----------------
extern "C" void kernel_launch(void* const* d_in, const int* in_sizes, int n_in,
                              void* d_out, int out_size, void* d_ws, size_t ws_size,
                              hipStream_t stream) {
  const float* x = (const float*)d_in[0];
  const int* ei = (const int*)d_in[1];
  const float* bw0 = (const float*)d_in[2];
  const float* sw0 = (const float*)d_in[3];
  const float* b0 = (const float*)d_in[4];
  const float* bw1 = (const float*)d_in[5];
  const float* sw1 = (const float*)d_in[6];
  const float* b1 = (const float*)d_in[7];
  const float* bwo = (const float*)d_in[8];
  const float* swo = (const float*)d_in[9];
  const float* bo = (const float*)d_in[10];
  const float* gamma = (const float*)d_in[11];
  const float* beta = (const float*)d_in[12];
  const int E = in_sizes[1] / 2;
  const int* esrc = ei;
  const int* edst = ei + E;

  char* ws = (char*)d_ws;
  size_t off = 0;
  auto alloc = [&](size_t bytes) -> void* {
    void* p = ws + off;
    off = (off + bytes + 255) & ~(size_t)255;
    return p;
  };
  _Float16* WPA0 = (_Float16*)alloc(196608 * 2);
  _Float16* WPA1 = (_Float16*)alloc(196608 * 2);
  _Float16* WPC = (_Float16*)alloc(65536 * 2);
  float* dinv = (float*)alloc(NN * 4);
  int* degE = (int*)alloc(NN * 4);
  int* rowptr = (int*)alloc((NN + 1) * 4);
  int* cursor = (int*)alloc(NN * 4);
  int* csr = (int*)alloc((size_t)E * 4);
  _Float16* A = (_Float16*)alloc((size_t)NN * 128 * 2);  // fp16 pre-scaled GEMM out
  float* h1 = (float*)alloc((size_t)NN * 128 * 4);       // h2 aliases h1
  float* P0 = (float*)alloc((size_t)NN * 64 * 4);
  float* P1 = (float*)alloc((size_t)NN * 64 * 4);
  _Float16* Ch = (_Float16*)alloc((size_t)NN * 64 * 2);
  float* partial = (float*)alloc((size_t)625 * 256 * 4);
  float* p2 = (float*)alloc((size_t)25 * 256 * 4);
  float* ssb = (float*)alloc(256 * 4);
  float* h2 = h1;
  (void)ws_size; (void)n_in; (void)out_size;

  int egrid = (E + 255) / 256;
  const int GG = 625;  // 625*32 = 20000 exactly

  packw_all<<<1872, 256, 0, stream>>>(bw0, sw0, bw1, sw1, bwo, swo, WPA0, WPA1, WPC,
                                      degE, ssb);
  count_deg<<<egrid, 256, 0, stream>>>(edst, degE, E);
  build_meta2<<<1, 1024, 0, stream>>>(degE, rowptr, cursor, dinv, NN);
  fill_csr<<<egrid, 256, 0, stream>>>(esrc, edst, cursor, csr, E);

  // layer 0 (+ out chunk 0): ssb = identity (written by packw_all)
  gemmSA<<<GG, 768, 0, stream>>>(x, ssb, WPA0, dinv, A, P0);
  aggregate128h<<<5000, 256, 0, stream>>>(A, rowptr, csr, dinv, b0, h1);
  bn_stats<<<625, 256, 0, stream>>>(h1, partial);
  bn_reduce<<<25, 256, 0, stream>>>(partial, p2);
  bn_final2<<<1, 256, 0, stream>>>(p2, gamma, beta, ssb);

  // layer 1 (+ out chunk 1)
  gemmSA<<<GG, 768, 0, stream>>>(h1, ssb, WPA1, dinv, A, P1);
  aggregate128h<<<5000, 256, 0, stream>>>(A, rowptr, csr, dinv, b1, h2);
  bn_stats<<<625, 256, 0, stream>>>(h2, partial);
  bn_reduce<<<25, 256, 0, stream>>>(partial, p2);
  bn_final2<<<1, 256, 0, stream>>>(p2, gamma, beta, ssb);

  // out chunk 2 + combine, then aggregate
  gemmSC<<<GG, 512, 0, stream>>>(h2, ssb, WPC, P0, P1, dinv, Ch);
  aggregate40h<<<5000, 256, 0, stream>>>(Ch, rowptr, csr, dinv, bo, (float*)d_out);
}

// Round 19
// 253.125 us; speedup vs baseline: 1.0193x; 1.0193x over previous
//
#include <hip/hip_runtime.h>

#define NN 20000

typedef _Float16 half8 __attribute__((ext_vector_type(8)));
typedef _Float16 half2v __attribute__((ext_vector_type(2)));
typedef float floatx16 __attribute__((ext_vector_type(16)));

#define MFMA32(a, b, c) __builtin_amdgcn_mfma_f32_32x32x16_f16((a), (b), (c), 0, 0, 0)
#define LD8(p) (*(const half8*)(p))

// async global->LDS: dest = wave-uniform base (+lane*16 by HW), src = per-lane
__device__ __forceinline__ void gl_lds16(const _Float16* g, _Float16* l) {
  __builtin_amdgcn_global_load_lds((const __attribute__((address_space(1))) char*)g,
                                   (__attribute__((address_space(3))) char*)l, 16, 0, 0);
}

// ---------------- closed-form cubic B-spline basis (knots -2.5+0.5k) ----------------
__device__ __forceinline__ void bspline7_fast(float x, float b[7]) {
  float u = (x + 2.5f) * 2.0f;
  float cf = floorf(u);
  int c = (int)cf;
  float t = u - cf;
  float omt = 1.0f - t;
  float t2 = t * t, t3 = t2 * t;
  float w0 = omt * omt * omt * (1.0f / 6.0f);
  float w1 = (3.0f * t3 - 6.0f * t2 + 4.0f) * (1.0f / 6.0f);
  float w2 = (-3.0f * t3 + 3.0f * t2 + 3.0f * t + 1.0f) * (1.0f / 6.0f);
  float w3 = t3 * (1.0f / 6.0f);
  bool valid = (c >= 0) && (c <= 9);
#pragma unroll
  for (int i = 0; i < 7; ++i) {
    int d = c - i;
    float w = (d == 0) ? w3 : (d == 1) ? w2 : (d == 2) ? w1 : (d == 3) ? w0 : 0.0f;
    b[i] = valid ? w : 0.0f;
  }
}

__device__ __forceinline__ float silu_f(float x) {
  return x * (1.0f / (1.0f + __expf(-x)));
}

__device__ __forceinline__ half8 afrag(float xv) {
  float b[7];
  bspline7_fast(xv, b);
  half8 hv;
  hv[0] = (_Float16)silu_f(xv);
#pragma unroll
  for (int k = 0; k < 7; ++k) hv[k + 1] = (_Float16)b[k];
  return hv;
}

// ---------------- feature build to GLOBAL, pre-swizzled granules ----------------
// Element (n,i) -> granule n*128 + (i ^ (n&7)); BN applied inline (identity for layer 0).
__global__ void fb_kernel(const float* __restrict__ X, const float* __restrict__ ss,
                          _Float16* __restrict__ F) {
  int idx = blockIdx.x * 256 + threadIdx.x;  // NN*128
  if (idx >= NN * 128) return;
  int n = idx >> 7, i = idx & 127;
  float xv = X[idx] * ss[i] + ss[128 + i];
  *(half8*)(F + ((size_t)n * 128 + (i ^ (n & 7))) * 8) = afrag(xv);
}

// ---------------- weight packs (32x32x16 B-fragments) + init tail ----------------
__global__ void packw_all(const float* __restrict__ Wb0, const float* __restrict__ Ws0,
                          const float* __restrict__ Wb1, const float* __restrict__ Ws1,
                          const float* __restrict__ WbO, const float* __restrict__ WsO,
                          _Float16* __restrict__ WPA0, _Float16* __restrict__ WPA1,
                          _Float16* __restrict__ WPC, int* __restrict__ degE,
                          float* __restrict__ ssb) {
  int bid = blockIdx.x;
  if (bid < 1536) {
    int s = (bid >= 768) ? 1 : 0;
    int idx = (bid - s * 768) * 256 + threadIdx.x;  // 64*6*64*8 = 196608
    if (idx >= 196608) return;
    const float* Wb = s ? Wb1 : Wb0;
    const float* Wsp = s ? Ws1 : Ws0;
    _Float16* WP = s ? WPA1 : WPA0;
    int j = idx & 7;
    int lane = (idx >> 3) & 63;
    int u = idx >> 9;  // ks*6 + cb32
    int cb = u % 6, ks = u / 6;
    int i = ks * 2 + (lane >> 5);
    int o32 = lane & 31;
    float v = 0.0f;
    if (cb < 4) {
      int o = cb * 32 + o32;
      v = (j == 0) ? Wb[(size_t)o * 128 + i] : Wsp[(size_t)o * 896 + i * 7 + (j - 1)];
    } else {
      int o = (cb - 4) * 32 + o32;
      if (o < 40)
        v = (j == 0) ? WbO[(size_t)o * 384 + s * 128 + i]
                     : WsO[(size_t)o * 2688 + s * 896 + i * 7 + (j - 1)];
    }
    WP[idx] = (_Float16)v;
  } else if (bid < 1792) {
    int idx = (bid - 1536) * 256 + threadIdx.x;  // 64*2*64*8 = 65536
    if (idx >= 65536) return;
    int j = idx & 7;
    int lane = (idx >> 3) & 63;
    int u = idx >> 9;  // ks*2 + cb32
    int cb = u & 1, ks = u >> 1;
    int i = ks * 2 + (lane >> 5);
    int o = cb * 32 + (lane & 31);
    float v = 0.0f;
    if (o < 40)
      v = (j == 0) ? WbO[(size_t)o * 384 + 2 * 128 + i]
                   : WsO[(size_t)o * 2688 + 2 * 896 + i * 7 + (j - 1)];
    WPC[idx] = (_Float16)v;
  } else if (bid < 1871) {
    int idx = (bid - 1792) * 256 + threadIdx.x;
    if (idx < NN) degE[idx] = 0;
  } else {
    int t = threadIdx.x;
    ssb[t] = (t < 128) ? 1.0f : 0.0f;  // identity BN for layer 0
  }
}

// ---------------- graph meta ----------------
__global__ void count_deg(const int* __restrict__ dst, int* __restrict__ degE, int E) {
  int e = blockIdx.x * 256 + threadIdx.x;
  if (e < E) atomicAdd(&degE[dst[e]], 1);
}

__global__ void build_meta2(const int* __restrict__ degE, int* __restrict__ rowptr,
                            int* __restrict__ cursor, float* __restrict__ dinv, int n) {
  __shared__ int wsum[16];
  int tid = threadIdx.x, lane = tid & 63, wid = tid >> 6;
  int i0 = tid * 20;
  int d[20];
  int s = 0;
#pragma unroll
  for (int j = 0; j < 20; ++j) {
    int i = i0 + j;
    int v = (i < n) ? degE[i] : 0;
    d[j] = v;
    s += v;
    if (i < n) dinv[i] = rsqrtf((float)(v + 1));  // +1 self loop
  }
  int val = s;
#pragma unroll
  for (int off = 1; off < 64; off <<= 1) {
    int t = __shfl_up(val, off);
    if (lane >= off) val += t;
  }
  if (lane == 63) wsum[wid] = val;
  __syncthreads();
  if (wid == 0) {
    int wv = (lane < 16) ? wsum[lane] : 0;
#pragma unroll
    for (int off = 1; off < 16; off <<= 1) {
      int t = __shfl_up(wv, off);
      if (lane >= off) wv += t;
    }
    if (lane < 16) wsum[lane] = wv;
  }
  __syncthreads();
  int base = (wid ? wsum[wid - 1] : 0) + val - s;
  if (tid == 0) rowptr[0] = 0;
#pragma unroll
  for (int j = 0; j < 20; ++j) {
    int i = i0 + j;
    if (i < n) {
      cursor[i] = base;
      rowptr[i + 1] = base + d[j];
      base += d[j];
    }
  }
}

__global__ void fill_csr(const int* __restrict__ src, const int* __restrict__ dst,
                         int* __restrict__ cursor, int* __restrict__ csr, int E) {
  int e = blockIdx.x * 256 + threadIdx.x;
  if (e < E) {
    int p = atomicAdd(&cursor[dst[e]], 1);
    csr[p] = src[e];
  }
}

// ---------------- GEMM: staged F (gl_lds) + MFMA32 + split-K x2 ----------------
// 768 thr = 12 waves: cb = w%6 (32-col block), kh = w/6 (K half, 32 ks each).
__global__ __launch_bounds__(768) void gemmTG(const _Float16* __restrict__ Fg,
                                              const _Float16* __restrict__ WP,
                                              const float* __restrict__ dinv,
                                              _Float16* __restrict__ A, float* __restrict__ P) {
  __shared__ _Float16 Fs[32 * 1024];  // 64 KB feature tile
  int tid = threadIdx.x;
  int lane = tid & 63, w = tid >> 6;
  int cb = w % 6, kh = w / 6;
  int row0 = blockIdx.x * 32;
  const _Float16* Ft = Fg + (size_t)row0 * 1024;
  for (int i = w; i < 64; i += 12) gl_lds16(Ft + (size_t)i * 512 + lane * 8, Fs + (size_t)i * 512);
  __syncthreads();  // drains vmcnt before barrier -> staging complete

  int r = lane & 31, hi = lane >> 5, rx = r & 7;
  const _Float16* Fr = Fs + (size_t)r * 1024;
  int ks0 = kh * 32;
  const _Float16* Bp = WP + (size_t)ks0 * 3072 + ((size_t)cb * 64 + lane) * 8;
  floatx16 acc = {};
#pragma unroll 4
  for (int k = 0; k < 32; ++k) {
    half8 a = LD8(Fr + (size_t)((2 * (ks0 + k) + hi) ^ rx) * 8);
    half8 b = LD8(Bp + (size_t)k * 3072);
    acc = MFMA32(a, b, acc);
  }
  __syncthreads();  // all waves done reading Fs
  float* red = (float*)Fs;
  if (kh == 1) {
#pragma unroll
    for (int q = 0; q < 16; ++q) red[q * 384 + cb * 64 + lane] = acc[q];
  }
  __syncthreads();
  if (kh == 0) {
    int col = lane & 31;
#pragma unroll
    for (int q = 0; q < 16; ++q) {
      float v = acc[q] + red[q * 384 + cb * 64 + lane];
      int rl = (q & 3) + 8 * (q >> 2) + 4 * hi;
      if (cb < 4)
        A[(size_t)(row0 + rl) * 128 + cb * 32 + col] = (_Float16)(v * dinv[row0 + rl]);
      else
        P[(size_t)(row0 + rl) * 64 + (cb - 4) * 32 + col] = v;
    }
  }
}

// output chunk 2: staged F + MFMA32 + split-K x4; + P0 + P1 -> Ch fp16
// 512 thr = 8 waves: cb = w&1, kh = w>>1 (16 ks each).
__global__ __launch_bounds__(512) void gemmTC2(const _Float16* __restrict__ Fg,
                                               const _Float16* __restrict__ WP,
                                               const float* __restrict__ P0,
                                               const float* __restrict__ P1,
                                               const float* __restrict__ dinv,
                                               _Float16* __restrict__ C) {
  __shared__ _Float16 Fs[32 * 1024];  // 64 KB
  int tid = threadIdx.x;
  int lane = tid & 63, w = tid >> 6;
  int cb = w & 1, kh = w >> 1;
  int row0 = blockIdx.x * 32;
  const _Float16* Ft = Fg + (size_t)row0 * 1024;
  for (int i = w; i < 64; i += 8) gl_lds16(Ft + (size_t)i * 512 + lane * 8, Fs + (size_t)i * 512);
  __syncthreads();

  int r = lane & 31, hi = lane >> 5, rx = r & 7;
  const _Float16* Fr = Fs + (size_t)r * 1024;
  int ks0 = kh * 16;
  const _Float16* Bp = WP + (size_t)ks0 * 1024 + ((size_t)cb * 64 + lane) * 8;
  floatx16 acc = {};
#pragma unroll 4
  for (int k = 0; k < 16; ++k) {
    half8 a = LD8(Fr + (size_t)((2 * (ks0 + k) + hi) ^ rx) * 8);
    half8 b = LD8(Bp + (size_t)k * 1024);
    acc = MFMA32(a, b, acc);
  }
  __syncthreads();  // all waves done reading Fs
  float* red = (float*)Fs;
  if (kh > 0) {
#pragma unroll
    for (int q = 0; q < 16; ++q)
      red[((kh - 1) * 16 + q) * 128 + cb * 64 + lane] = acc[q];
  }
  __syncthreads();
  if (kh == 0) {
    int col = lane & 31;
#pragma unroll
    for (int q = 0; q < 16; ++q) {
      float v = acc[q] + red[q * 128 + cb * 64 + lane] +
                red[(16 + q) * 128 + cb * 64 + lane] + red[(32 + q) * 128 + cb * 64 + lane];
      int rl = (q & 3) + 8 * (q >> 2) + 4 * hi;
      size_t idx = (size_t)(row0 + rl) * 64 + cb * 32 + col;
      C[idx] = (_Float16)((v + P0[idx] + P1[idx]) * dinv[row0 + rl]);
    }
  }
}

// ---------------- aggregation: wave per node, pre-scaled fp16 rows, 4-way ILP ----------------
__global__ __launch_bounds__(256) void aggregate128h(const _Float16* __restrict__ Ah,
                                                     const int* __restrict__ rowptr,
                                                     const int* __restrict__ csr,
                                                     const float* __restrict__ dinv,
                                                     const float* __restrict__ bias,
                                                     float* __restrict__ Y) {
  int wid = threadIdx.x >> 6, lane = threadIdx.x & 63;
  int n = blockIdx.x * 4 + wid;  // grid 5000 -> n < 20000
  float di = dinv[n];
  half2v self = *(const half2v*)(Ah + (size_t)n * 128 + lane * 2);
  float a0 = (float)self[0], a1 = (float)self[1];
  float b0x = 0, b0y = 0, b1x = 0, b1y = 0, b2x = 0, b2y = 0, b3x = 0, b3y = 0;
  int e0 = rowptr[n], m = rowptr[n + 1] - e0;
  int j = 0;
  for (; j + 4 <= m; j += 4) {
    int s0 = csr[e0 + j], s1 = csr[e0 + j + 1], s2 = csr[e0 + j + 2], s3 = csr[e0 + j + 3];
    half2v r0 = *(const half2v*)(Ah + (size_t)s0 * 128 + lane * 2);
    half2v r1 = *(const half2v*)(Ah + (size_t)s1 * 128 + lane * 2);
    half2v r2 = *(const half2v*)(Ah + (size_t)s2 * 128 + lane * 2);
    half2v r3 = *(const half2v*)(Ah + (size_t)s3 * 128 + lane * 2);
    b0x += (float)r0[0]; b0y += (float)r0[1];
    b1x += (float)r1[0]; b1y += (float)r1[1];
    b2x += (float)r2[0]; b2y += (float)r2[1];
    b3x += (float)r3[0]; b3y += (float)r3[1];
  }
  for (; j < m; ++j) {
    int s = csr[e0 + j];
    half2v rr = *(const half2v*)(Ah + (size_t)s * 128 + lane * 2);
    b0x += (float)rr[0]; b0y += (float)rr[1];
  }
  a0 += (b0x + b1x) + (b2x + b3x);
  a1 += (b0y + b1y) + (b2y + b3y);
  float2 outv = {a0 * di + bias[lane * 2], a1 * di + bias[lane * 2 + 1]};
  *(float2*)(Y + (size_t)n * 128 + lane * 2) = outv;
}

__global__ __launch_bounds__(256) void aggregate40h(const _Float16* __restrict__ Ch,
                                                    const int* __restrict__ rowptr,
                                                    const int* __restrict__ csr,
                                                    const float* __restrict__ dinv,
                                                    const float* __restrict__ bias,
                                                    float* __restrict__ out) {
  int wid = threadIdx.x >> 6, lane = threadIdx.x & 63;
  int n = blockIdx.x * 4 + wid;
  float di = dinv[n];
  float a = (float)Ch[(size_t)n * 64 + lane];
  float b0 = 0, b1 = 0, b2 = 0, b3 = 0;
  int e0 = rowptr[n], m = rowptr[n + 1] - e0;
  int j = 0;
  for (; j + 4 <= m; j += 4) {
    int s0 = csr[e0 + j], s1 = csr[e0 + j + 1], s2 = csr[e0 + j + 2], s3 = csr[e0 + j + 3];
    b0 += (float)Ch[(size_t)s0 * 64 + lane];
    b1 += (float)Ch[(size_t)s1 * 64 + lane];
    b2 += (float)Ch[(size_t)s2 * 64 + lane];
    b3 += (float)Ch[(size_t)s3 * 64 + lane];
  }
  for (; j < m; ++j) {
    int s = csr[e0 + j];
    b0 += (float)Ch[(size_t)s * 64 + lane];
  }
  a += (b0 + b1) + (b2 + b3);
  if (lane < 40) out[(size_t)n * 40 + lane] = a * di + bias[lane];
}

// ---------------- batchnorm: 3-stage deterministic tree ----------------
__global__ __launch_bounds__(256) void bn_stats(const float* __restrict__ H,
                                                float* __restrict__ partial) {
  int tid = threadIdx.x;
  int c4 = (tid & 31) * 4;
  int r0 = blockIdx.x * 32 + (tid >> 5) * 4;
  float s0 = 0, s1 = 0, s2 = 0, s3 = 0, q0 = 0, q1 = 0, q2 = 0, q3 = 0;
#pragma unroll
  for (int j = 0; j < 4; ++j) {
    float4 v = *(const float4*)(H + (size_t)(r0 + j) * 128 + c4);
    s0 += v.x; s1 += v.y; s2 += v.z; s3 += v.w;
    q0 += v.x * v.x; q1 += v.y * v.y; q2 += v.z * v.z; q3 += v.w * v.w;
  }
  __shared__ float sh[2][256][4];
  sh[0][tid][0] = s0; sh[0][tid][1] = s1; sh[0][tid][2] = s2; sh[0][tid][3] = s3;
  sh[1][tid][0] = q0; sh[1][tid][1] = q1; sh[1][tid][2] = q2; sh[1][tid][3] = q3;
  __syncthreads();
  if (tid < 32) {
    float a0 = 0, a1 = 0, a2 = 0, a3 = 0, b0 = 0, b1 = 0, b2 = 0, b3 = 0;
#pragma unroll
    for (int g = 0; g < 8; ++g) {
      int u = g * 32 + tid;
      a0 += sh[0][u][0]; a1 += sh[0][u][1]; a2 += sh[0][u][2]; a3 += sh[0][u][3];
      b0 += sh[1][u][0]; b1 += sh[1][u][1]; b2 += sh[1][u][2]; b3 += sh[1][u][3];
    }
    float* p = partial + (size_t)blockIdx.x * 256;
    p[tid * 4 + 0] = a0; p[tid * 4 + 1] = a1; p[tid * 4 + 2] = a2; p[tid * 4 + 3] = a3;
    p[128 + tid * 4 + 0] = b0; p[128 + tid * 4 + 1] = b1;
    p[128 + tid * 4 + 2] = b2; p[128 + tid * 4 + 3] = b3;
  }
}

__global__ __launch_bounds__(256) void bn_reduce(const float* __restrict__ partial,
                                                 float* __restrict__ p2) {
  int tid = threadIdx.x;
  const float* base = partial + (size_t)blockIdx.x * 25 * 256 + tid;
  float a0 = 0, a1 = 0, a2 = 0, a3 = 0, a4 = 0;
#pragma unroll
  for (int j = 0; j < 5; ++j) {
    a0 += base[(j * 5 + 0) * 256];
    a1 += base[(j * 5 + 1) * 256];
    a2 += base[(j * 5 + 2) * 256];
    a3 += base[(j * 5 + 3) * 256];
    a4 += base[(j * 5 + 4) * 256];
  }
  p2[(size_t)blockIdx.x * 256 + tid] = ((a0 + a1) + (a2 + a3)) + a4;
}

__global__ __launch_bounds__(256) void bn_final2(const float* __restrict__ p2,
                                                 const float* __restrict__ gamma,
                                                 const float* __restrict__ beta,
                                                 float* __restrict__ ss) {
  int tid = threadIdx.x;
  double a0 = 0, a1 = 0, a2 = 0, a3 = 0, a4 = 0;
#pragma unroll
  for (int j = 0; j < 5; ++j) {
    a0 += (double)p2[(size_t)(j * 5 + 0) * 256 + tid];
    a1 += (double)p2[(size_t)(j * 5 + 1) * 256 + tid];
    a2 += (double)p2[(size_t)(j * 5 + 2) * 256 + tid];
    a3 += (double)p2[(size_t)(j * 5 + 3) * 256 + tid];
    a4 += (double)p2[(size_t)(j * 5 + 4) * 256 + tid];
  }
  double tot = ((a0 + a1) + (a2 + a3)) + a4;
  __shared__ double sh[256];
  sh[tid] = tot;
  __syncthreads();
  if (tid < 128) {
    double S = sh[tid];
    double Q = sh[128 + tid];
    double mean = S / (double)NN;
    double var = Q / (double)NN - mean * mean;
    float sc = gamma[tid] * rsqrtf((float)var + 1e-5f);
    ss[tid] = sc;
    ss[128 + tid] = beta[tid] - (float)mean * sc;
  }
}

// ---------------- launch ----------------
extern "C" void kernel_launch(void* const* d_in, const int* in_sizes, int n_in,
                              void* d_out, int out_size, void* d_ws, size_t ws_size,
                              hipStream_t stream) {
  const float* x = (const float*)d_in[0];
  const int* ei = (const int*)d_in[1];
  const float* bw0 = (const float*)d_in[2];
  const float* sw0 = (const float*)d_in[3];
  const float* b0 = (const float*)d_in[4];
  const float* bw1 = (const float*)d_in[5];
  const float* sw1 = (const float*)d_in[6];
  const float* b1 = (const float*)d_in[7];
  const float* bwo = (const float*)d_in[8];
  const float* swo = (const float*)d_in[9];
  const float* bo = (const float*)d_in[10];
  const float* gamma = (const float*)d_in[11];
  const float* beta = (const float*)d_in[12];
  const int E = in_sizes[1] / 2;
  const int* esrc = ei;
  const int* edst = ei + E;

  char* ws = (char*)d_ws;
  size_t off = 0;
  auto alloc = [&](size_t bytes) -> void* {
    void* p = ws + off;
    off = (off + bytes + 255) & ~(size_t)255;
    return p;
  };
  _Float16* WPA0 = (_Float16*)alloc(196608 * 2);
  _Float16* WPA1 = (_Float16*)alloc(196608 * 2);
  _Float16* WPC = (_Float16*)alloc(65536 * 2);
  float* dinv = (float*)alloc(NN * 4);
  int* degE = (int*)alloc(NN * 4);
  int* rowptr = (int*)alloc((NN + 1) * 4);
  int* cursor = (int*)alloc(NN * 4);
  int* csr = (int*)alloc((size_t)E * 4);
  _Float16* Fg = (_Float16*)alloc((size_t)NN * 1024 * 2);  // 41 MB feature granules
  _Float16* A = (_Float16*)alloc((size_t)NN * 128 * 2);    // fp16 pre-scaled GEMM out
  float* h1 = (float*)alloc((size_t)NN * 128 * 4);         // h2 aliases h1
  float* P0 = (float*)alloc((size_t)NN * 64 * 4);
  float* P1 = (float*)alloc((size_t)NN * 64 * 4);
  _Float16* Ch = (_Float16*)alloc((size_t)NN * 64 * 2);
  float* partial = (float*)alloc((size_t)625 * 256 * 4);
  float* p2 = (float*)alloc((size_t)25 * 256 * 4);
  float* ssb = (float*)alloc(256 * 4);
  float* h2 = h1;
  (void)ws_size; (void)n_in; (void)out_size;

  int egrid = (E + 255) / 256;
  const int GG = 625;  // 625*32 = 20000 exactly

  packw_all<<<1872, 256, 0, stream>>>(bw0, sw0, bw1, sw1, bwo, swo, WPA0, WPA1, WPC,
                                      degE, ssb);
  count_deg<<<egrid, 256, 0, stream>>>(edst, degE, E);
  build_meta2<<<1, 1024, 0, stream>>>(degE, rowptr, cursor, dinv, NN);
  fill_csr<<<egrid, 256, 0, stream>>>(esrc, edst, cursor, csr, E);

  // layer 0 (+ out chunk 0): ssb = identity (written by packw_all)
  fb_kernel<<<10000, 256, 0, stream>>>(x, ssb, Fg);
  gemmTG<<<GG, 768, 0, stream>>>(Fg, WPA0, dinv, A, P0);
  aggregate128h<<<5000, 256, 0, stream>>>(A, rowptr, csr, dinv, b0, h1);
  bn_stats<<<625, 256, 0, stream>>>(h1, partial);
  bn_reduce<<<25, 256, 0, stream>>>(partial, p2);
  bn_final2<<<1, 256, 0, stream>>>(p2, gamma, beta, ssb);

  // layer 1 (+ out chunk 1)
  fb_kernel<<<10000, 256, 0, stream>>>(h1, ssb, Fg);
  gemmTG<<<GG, 768, 0, stream>>>(Fg, WPA1, dinv, A, P1);
  aggregate128h<<<5000, 256, 0, stream>>>(A, rowptr, csr, dinv, b1, h2);
  bn_stats<<<625, 256, 0, stream>>>(h2, partial);
  bn_reduce<<<25, 256, 0, stream>>>(partial, p2);
  bn_final2<<<1, 256, 0, stream>>>(p2, gamma, beta, ssb);

  // out chunk 2 + combine, then aggregate
  fb_kernel<<<10000, 256, 0, stream>>>(h2, ssb, Fg);
  gemmTC2<<<GG, 512, 0, stream>>>(Fg, WPC, P0, P1, dinv, Ch);
  aggregate40h<<<5000, 256, 0, stream>>>(Ch, rowptr, csr, dinv, bo, (float*)d_out);
}

// Round 20
// 253.045 us; speedup vs baseline: 1.0197x; 1.0003x over previous
//
#include <hip/hip_runtime.h>

#define NN 20000

typedef _Float16 half8 __attribute__((ext_vector_type(8)));
typedef _Float16 half2v __attribute__((ext_vector_type(2)));
typedef float floatx16 __attribute__((ext_vector_type(16)));

#define MFMA32(a, b, c) __builtin_amdgcn_mfma_f32_32x32x16_f16((a), (b), (c), 0, 0, 0)
#define LD8(p) (*(const half8*)(p))

// ---------------- closed-form cubic B-spline basis (knots -2.5+0.5k) ----------------
__device__ __forceinline__ void bspline7_fast(float x, float b[7]) {
  float u = (x + 2.5f) * 2.0f;
  float cf = floorf(u);
  int c = (int)cf;
  float t = u - cf;
  float omt = 1.0f - t;
  float t2 = t * t, t3 = t2 * t;
  float w0 = omt * omt * omt * (1.0f / 6.0f);
  float w1 = (3.0f * t3 - 6.0f * t2 + 4.0f) * (1.0f / 6.0f);
  float w2 = (-3.0f * t3 + 3.0f * t2 + 3.0f * t + 1.0f) * (1.0f / 6.0f);
  float w3 = t3 * (1.0f / 6.0f);
  bool valid = (c >= 0) && (c <= 9);
#pragma unroll
  for (int i = 0; i < 7; ++i) {
    int d = c - i;
    float w = (d == 0) ? w3 : (d == 1) ? w2 : (d == 2) ? w1 : (d == 3) ? w0 : 0.0f;
    b[i] = valid ? w : 0.0f;
  }
}

__device__ __forceinline__ float silu_f(float x) {
  return x * (1.0f / (1.0f + __expf(-x)));
}

__device__ __forceinline__ half8 afrag(float xv) {
  float b[7];
  bspline7_fast(xv, b);
  half8 hv;
  hv[0] = (_Float16)silu_f(xv);
#pragma unroll
  for (int k = 0; k < 7; ++k) hv[k + 1] = (_Float16)b[k];
  return hv;
}

// ---------------- weight packs (32x32x16 B-fragments) + init tail ----------------
// blocks 0..1535: WPA0/1; 1536..1791: WPC; 1792..1870: zero degE; 1871: ssb + partial pad.
__global__ void packw_all(const float* __restrict__ Wb0, const float* __restrict__ Ws0,
                          const float* __restrict__ Wb1, const float* __restrict__ Ws1,
                          const float* __restrict__ WbO, const float* __restrict__ WsO,
                          _Float16* __restrict__ WPA0, _Float16* __restrict__ WPA1,
                          _Float16* __restrict__ WPC, int* __restrict__ degE,
                          float* __restrict__ ssb, float* __restrict__ partial) {
  int bid = blockIdx.x;
  if (bid < 1536) {
    int s = (bid >= 768) ? 1 : 0;
    int idx = (bid - s * 768) * 256 + threadIdx.x;  // 64*6*64*8 = 196608
    if (idx >= 196608) return;
    const float* Wb = s ? Wb1 : Wb0;
    const float* Wsp = s ? Ws1 : Ws0;
    _Float16* WP = s ? WPA1 : WPA0;
    int j = idx & 7;
    int lane = (idx >> 3) & 63;
    int u = idx >> 9;  // ks*6 + cb32
    int cb = u % 6, ks = u / 6;
    int i = ks * 2 + (lane >> 5);
    int o32 = lane & 31;
    float v = 0.0f;
    if (cb < 4) {
      int o = cb * 32 + o32;
      v = (j == 0) ? Wb[(size_t)o * 128 + i] : Wsp[(size_t)o * 896 + i * 7 + (j - 1)];
    } else {
      int o = (cb - 4) * 32 + o32;
      if (o < 40)
        v = (j == 0) ? WbO[(size_t)o * 384 + s * 128 + i]
                     : WsO[(size_t)o * 2688 + s * 896 + i * 7 + (j - 1)];
    }
    WP[idx] = (_Float16)v;
  } else if (bid < 1792) {
    int idx = (bid - 1536) * 256 + threadIdx.x;  // 64*2*64*8 = 65536
    if (idx >= 65536) return;
    int j = idx & 7;
    int lane = (idx >> 3) & 63;
    int u = idx >> 9;  // ks*2 + cb32
    int cb = u & 1, ks = u >> 1;
    int i = ks * 2 + (lane >> 5);
    int o = cb * 32 + (lane & 31);
    float v = 0.0f;
    if (o < 40)
      v = (j == 0) ? WbO[(size_t)o * 384 + 2 * 128 + i]
                   : WsO[(size_t)o * 2688 + 2 * 896 + i * 7 + (j - 1)];
    WPC[idx] = (_Float16)v;
  } else if (bid < 1871) {
    int idx = (bid - 1792) * 256 + threadIdx.x;
    if (idx < NN) degE[idx] = 0;
  } else {
    int t = threadIdx.x;
    ssb[t] = (t < 128) ? 1.0f : 0.0f;  // identity BN for layer 0
    for (int rr = 625; rr < 640; ++rr) partial[(size_t)rr * 256 + t] = 0.0f;  // pad rows
  }
}

// ---------------- graph meta ----------------
__global__ void count_deg(const int* __restrict__ dst, int* __restrict__ degE, int E) {
  int e = blockIdx.x * 256 + threadIdx.x;
  if (e < E) atomicAdd(&degE[dst[e]], 1);
}

__global__ void build_meta2(const int* __restrict__ degE, int* __restrict__ rowptr,
                            int* __restrict__ cursor, float* __restrict__ dinv, int n) {
  __shared__ int wsum[16];
  int tid = threadIdx.x, lane = tid & 63, wid = tid >> 6;
  int i0 = tid * 20;
  int d[20];
  int s = 0;
#pragma unroll
  for (int j = 0; j < 20; ++j) {
    int i = i0 + j;
    int v = (i < n) ? degE[i] : 0;
    d[j] = v;
    s += v;
    if (i < n) dinv[i] = rsqrtf((float)(v + 1));  // +1 self loop
  }
  int val = s;
#pragma unroll
  for (int off = 1; off < 64; off <<= 1) {
    int t = __shfl_up(val, off);
    if (lane >= off) val += t;
  }
  if (lane == 63) wsum[wid] = val;
  __syncthreads();
  if (wid == 0) {
    int wv = (lane < 16) ? wsum[lane] : 0;
#pragma unroll
    for (int off = 1; off < 16; off <<= 1) {
      int t = __shfl_up(wv, off);
      if (lane >= off) wv += t;
    }
    if (lane < 16) wsum[lane] = wv;
  }
  __syncthreads();
  int base = (wid ? wsum[wid - 1] : 0) + val - s;
  if (tid == 0) rowptr[0] = 0;
#pragma unroll
  for (int j = 0; j < 20; ++j) {
    int i = i0 + j;
    if (i < n) {
      cursor[i] = base;
      rowptr[i + 1] = base + d[j];
      base += d[j];
    }
  }
}

__global__ void fill_csr(const int* __restrict__ src, const int* __restrict__ dst,
                         int* __restrict__ cursor, int* __restrict__ csr, int E) {
  int e = blockIdx.x * 256 + threadIdx.x;
  if (e < E) {
    int p = atomicAdd(&cursor[dst[e]], 1);
    csr[p] = src[e];
  }
}

// ---------------- KAN GEMM: fused build + MFMA32 + split-K x2 (r17 exact) ----------------
__global__ __launch_bounds__(768) void gemmSA(const float* __restrict__ X,
                                              const float* __restrict__ ss,
                                              const _Float16* __restrict__ WP,
                                              const float* __restrict__ dinv,
                                              _Float16* __restrict__ A, _Float16* __restrict__ P) {
  __shared__ _Float16 Fs[32 * 1024];  // 64 KB
  int tid = threadIdx.x;
  int lane = tid & 63, w = tid >> 6;
  int cb = w % 6, kh = w / 6;
  int row0 = blockIdx.x * 32;
  for (int idx = tid; idx < 4096; idx += 768) {
    int r = idx >> 7, i = idx & 127;
    float xv = X[(size_t)(row0 + r) * 128 + i] * ss[i] + ss[128 + i];
    *(half8*)(Fs + ((size_t)r * 128 + (i ^ (r & 7))) * 8) = afrag(xv);
  }
  __syncthreads();

  int r = lane & 31, hi = lane >> 5, rx = r & 7;
  const _Float16* Fr = Fs + (size_t)r * 1024;
  const _Float16* Bp = WP + ((size_t)cb * 64 + lane) * 8;  // stride 3072 per ks
  floatx16 acc = {};
  int ks0 = kh * 32;
#pragma unroll 4
  for (int ks = ks0; ks < ks0 + 32; ++ks) {
    half8 a = LD8(Fr + (size_t)((2 * ks + hi) ^ rx) * 8);
    half8 b = LD8(Bp + (size_t)ks * 3072);
    acc = MFMA32(a, b, acc);
  }
  __syncthreads();  // all waves done reading Fs
  float* red = (float*)Fs;
  if (kh == 1) {
#pragma unroll
    for (int q = 0; q < 16; ++q) red[q * 384 + cb * 64 + lane] = acc[q];
  }
  __syncthreads();
  if (kh == 0) {
    int col = lane & 31;
#pragma unroll
    for (int q = 0; q < 16; ++q) {
      float v = acc[q] + red[q * 384 + cb * 64 + lane];
      int rl = (q & 3) + 8 * (q >> 2) + 4 * hi;
      if (cb < 4)
        A[(size_t)(row0 + rl) * 128 + cb * 32 + col] = (_Float16)(v * dinv[row0 + rl]);
      else
        P[(size_t)(row0 + rl) * 64 + (cb - 4) * 32 + col] = (_Float16)v;
    }
  }
}

// output chunk 2: fused build + MFMA32 + split-K x4 (r17 exact, fp16 partials)
__global__ __launch_bounds__(512) void gemmSC(const float* __restrict__ X,
                                              const float* __restrict__ ss,
                                              const _Float16* __restrict__ WP,
                                              const _Float16* __restrict__ P0,
                                              const _Float16* __restrict__ P1,
                                              const float* __restrict__ dinv,
                                              _Float16* __restrict__ C) {
  __shared__ _Float16 Fs[32 * 1024];  // 64 KB
  int tid = threadIdx.x;
  int lane = tid & 63, w = tid >> 6;
  int cb = w & 1, kh = w >> 1;
  int row0 = blockIdx.x * 32;
  for (int idx = tid; idx < 4096; idx += 512) {
    int r = idx >> 7, i = idx & 127;
    float xv = X[(size_t)(row0 + r) * 128 + i] * ss[i] + ss[128 + i];
    *(half8*)(Fs + ((size_t)r * 128 + (i ^ (r & 7))) * 8) = afrag(xv);
  }
  __syncthreads();

  int r = lane & 31, hi = lane >> 5, rx = r & 7;
  const _Float16* Fr = Fs + (size_t)r * 1024;
  const _Float16* Bp = WP + ((size_t)cb * 64 + lane) * 8;  // stride 1024 per ks
  floatx16 acc = {};
  int ks0 = kh * 16;
#pragma unroll 4
  for (int ks = ks0; ks < ks0 + 16; ++ks) {
    half8 a = LD8(Fr + (size_t)((2 * ks + hi) ^ rx) * 8);
    half8 b = LD8(Bp + (size_t)ks * 1024);
    acc = MFMA32(a, b, acc);
  }
  __syncthreads();  // all waves done reading Fs
  float* red = (float*)Fs;
  if (kh > 0) {
#pragma unroll
    for (int q = 0; q < 16; ++q)
      red[((kh - 1) * 16 + q) * 128 + cb * 64 + lane] = acc[q];
  }
  __syncthreads();
  if (kh == 0) {
    int col = lane & 31;
#pragma unroll
    for (int q = 0; q < 16; ++q) {
      float v = acc[q] + red[q * 128 + cb * 64 + lane] +
                red[(16 + q) * 128 + cb * 64 + lane] + red[(32 + q) * 128 + cb * 64 + lane];
      int rl = (q & 3) + 8 * (q >> 2) + 4 * hi;
      size_t idx = (size_t)(row0 + rl) * 64 + cb * 32 + col;
      C[idx] = (_Float16)((v + (float)P0[idx] + (float)P1[idx]) * dinv[row0 + rl]);
    }
  }
}

// ---------------- aggregation: wave per node, pre-scaled fp16 rows, 8-way ILP ----------------
__global__ __launch_bounds__(256) void aggregate128h(const _Float16* __restrict__ Ah,
                                                     const int* __restrict__ rowptr,
                                                     const int* __restrict__ csr,
                                                     const float* __restrict__ dinv,
                                                     const float* __restrict__ bias,
                                                     float* __restrict__ Y) {
  int wid = threadIdx.x >> 6, lane = threadIdx.x & 63;
  int n = blockIdx.x * 4 + wid;  // grid 5000 -> n < 20000
  float di = dinv[n];
  half2v self = *(const half2v*)(Ah + (size_t)n * 128 + lane * 2);
  float a0 = (float)self[0], a1 = (float)self[1];
  float bx[8] = {0, 0, 0, 0, 0, 0, 0, 0}, by[8] = {0, 0, 0, 0, 0, 0, 0, 0};
  int e0 = rowptr[n], m = rowptr[n + 1] - e0;
  int j = 0;
  for (; j + 8 <= m; j += 8) {
    int s[8];
#pragma unroll
    for (int q = 0; q < 8; ++q) s[q] = csr[e0 + j + q];
#pragma unroll
    for (int q = 0; q < 8; ++q) {
      half2v rr = *(const half2v*)(Ah + (size_t)s[q] * 128 + lane * 2);
      bx[q] += (float)rr[0];
      by[q] += (float)rr[1];
    }
  }
  for (; j < m; ++j) {
    int s = csr[e0 + j];
    half2v rr = *(const half2v*)(Ah + (size_t)s * 128 + lane * 2);
    bx[0] += (float)rr[0];
    by[0] += (float)rr[1];
  }
  a0 += ((bx[0] + bx[1]) + (bx[2] + bx[3])) + ((bx[4] + bx[5]) + (bx[6] + bx[7]));
  a1 += ((by[0] + by[1]) + (by[2] + by[3])) + ((by[4] + by[5]) + (by[6] + by[7]));
  float2 outv = {a0 * di + bias[lane * 2], a1 * di + bias[lane * 2 + 1]};
  *(float2*)(Y + (size_t)n * 128 + lane * 2) = outv;
}

__global__ __launch_bounds__(256) void aggregate40h(const _Float16* __restrict__ Ch,
                                                    const int* __restrict__ rowptr,
                                                    const int* __restrict__ csr,
                                                    const float* __restrict__ dinv,
                                                    const float* __restrict__ bias,
                                                    float* __restrict__ out) {
  int wid = threadIdx.x >> 6, lane = threadIdx.x & 63;
  int n = blockIdx.x * 4 + wid;
  float di = dinv[n];
  float a = (float)Ch[(size_t)n * 64 + lane];
  float b[8] = {0, 0, 0, 0, 0, 0, 0, 0};
  int e0 = rowptr[n], m = rowptr[n + 1] - e0;
  int j = 0;
  for (; j + 8 <= m; j += 8) {
    int s[8];
#pragma unroll
    for (int q = 0; q < 8; ++q) s[q] = csr[e0 + j + q];
#pragma unroll
    for (int q = 0; q < 8; ++q) b[q] += (float)Ch[(size_t)s[q] * 64 + lane];
  }
  for (; j < m; ++j) {
    int s = csr[e0 + j];
    b[0] += (float)Ch[(size_t)s * 64 + lane];
  }
  a += ((b[0] + b[1]) + (b[2] + b[3])) + ((b[4] + b[5]) + (b[6] + b[7]));
  if (lane < 40) out[(size_t)n * 40 + lane] = a * di + bias[lane];
}

// ---------------- batchnorm: stats (625 blocks) + single-dispatch finalize ----------------
__global__ __launch_bounds__(256) void bn_stats(const float* __restrict__ H,
                                                float* __restrict__ partial) {
  int tid = threadIdx.x;
  int c4 = (tid & 31) * 4;
  int r0 = blockIdx.x * 32 + (tid >> 5) * 4;
  float s0 = 0, s1 = 0, s2 = 0, s3 = 0, q0 = 0, q1 = 0, q2 = 0, q3 = 0;
#pragma unroll
  for (int j = 0; j < 4; ++j) {
    float4 v = *(const float4*)(H + (size_t)(r0 + j) * 128 + c4);
    s0 += v.x; s1 += v.y; s2 += v.z; s3 += v.w;
    q0 += v.x * v.x; q1 += v.y * v.y; q2 += v.z * v.z; q3 += v.w * v.w;
  }
  __shared__ float sh[2][256][4];
  sh[0][tid][0] = s0; sh[0][tid][1] = s1; sh[0][tid][2] = s2; sh[0][tid][3] = s3;
  sh[1][tid][0] = q0; sh[1][tid][1] = q1; sh[1][tid][2] = q2; sh[1][tid][3] = q3;
  __syncthreads();
  if (tid < 32) {
    float a0 = 0, a1 = 0, a2 = 0, a3 = 0, b0 = 0, b1 = 0, b2 = 0, b3 = 0;
#pragma unroll
    for (int g = 0; g < 8; ++g) {
      int u = g * 32 + tid;
      a0 += sh[0][u][0]; a1 += sh[0][u][1]; a2 += sh[0][u][2]; a3 += sh[0][u][3];
      b0 += sh[1][u][0]; b1 += sh[1][u][1]; b2 += sh[1][u][2]; b3 += sh[1][u][3];
    }
    float* p = partial + (size_t)blockIdx.x * 256;
    p[tid * 4 + 0] = a0; p[tid * 4 + 1] = a1; p[tid * 4 + 2] = a2; p[tid * 4 + 3] = a3;
    p[128 + tid * 4 + 0] = b0; p[128 + tid * 4 + 1] = b1;
    p[128 + tid * 4 + 2] = b2; p[128 + tid * 4 + 3] = b3;
  }
}

// 1 block, 1024 thr = 256 cols x 4 row-groups; rows padded to 640 (rows 625..639 zero).
// Row-group rg sums rows rg+4*(5j+q), q=0..4, j=0..31 -> 160 rows each, fixed order.
__global__ __launch_bounds__(1024) void bn_finalB(const float* __restrict__ partial,
                                                  const float* __restrict__ gamma,
                                                  const float* __restrict__ beta,
                                                  float* __restrict__ ss) {
  int tid = threadIdx.x;
  int col = tid & 255, rg = tid >> 8;
  const float* base = partial + (size_t)rg * 256 + col;
  double a0 = 0, a1 = 0, a2 = 0, a3 = 0, a4 = 0;
  for (int j = 0; j < 32; ++j) {
    size_t rbase = (size_t)(20 * j) * 256;
    a0 += (double)base[rbase];
    a1 += (double)base[rbase + 4 * 256];
    a2 += (double)base[rbase + 8 * 256];
    a3 += (double)base[rbase + 12 * 256];
    a4 += (double)base[rbase + 16 * 256];
  }
  double tot = ((a0 + a1) + (a2 + a3)) + a4;
  __shared__ double shd[4][256];
  shd[rg][col] = tot;
  __syncthreads();
  if (tid < 256) shd[0][tid] = (shd[0][tid] + shd[1][tid]) + (shd[2][tid] + shd[3][tid]);
  __syncthreads();
  if (tid < 128) {
    double S = shd[0][tid];
    double Q = shd[0][128 + tid];
    double mean = S / (double)NN;
    double var = Q / (double)NN - mean * mean;
    float sc = gamma[tid] * rsqrtf((float)var + 1e-5f);
    ss[tid] = sc;
    ss[128 + tid] = beta[tid] - (float)mean * sc;
  }
}

// ---------------- launch ----------------
extern "C" void kernel_launch(void* const* d_in, const int* in_sizes, int n_in,
                              void* d_out, int out_size, void* d_ws, size_t ws_size,
                              hipStream_t stream) {
  const float* x = (const float*)d_in[0];
  const int* ei = (const int*)d_in[1];
  const float* bw0 = (const float*)d_in[2];
  const float* sw0 = (const float*)d_in[3];
  const float* b0 = (const float*)d_in[4];
  const float* bw1 = (const float*)d_in[5];
  const float* sw1 = (const float*)d_in[6];
  const float* b1 = (const float*)d_in[7];
  const float* bwo = (const float*)d_in[8];
  const float* swo = (const float*)d_in[9];
  const float* bo = (const float*)d_in[10];
  const float* gamma = (const float*)d_in[11];
  const float* beta = (const float*)d_in[12];
  const int E = in_sizes[1] / 2;
  const int* esrc = ei;
  const int* edst = ei + E;

  char* ws = (char*)d_ws;
  size_t off = 0;
  auto alloc = [&](size_t bytes) -> void* {
    void* p = ws + off;
    off = (off + bytes + 255) & ~(size_t)255;
    return p;
  };
  _Float16* WPA0 = (_Float16*)alloc(196608 * 2);
  _Float16* WPA1 = (_Float16*)alloc(196608 * 2);
  _Float16* WPC = (_Float16*)alloc(65536 * 2);
  float* dinv = (float*)alloc(NN * 4);
  int* degE = (int*)alloc(NN * 4);
  int* rowptr = (int*)alloc((NN + 1) * 4);
  int* cursor = (int*)alloc(NN * 4);
  int* csr = (int*)alloc((size_t)E * 4);
  _Float16* A = (_Float16*)alloc((size_t)NN * 128 * 2);   // fp16 pre-scaled GEMM out
  float* h1 = (float*)alloc((size_t)NN * 128 * 4);        // h2 aliases h1
  _Float16* P0 = (_Float16*)alloc((size_t)NN * 64 * 2);   // fp16 out-chunk partials
  _Float16* P1 = (_Float16*)alloc((size_t)NN * 64 * 2);
  _Float16* Ch = (_Float16*)alloc((size_t)NN * 64 * 2);
  float* partial = (float*)alloc((size_t)640 * 256 * 4);  // 625 rows + 15 zero pad rows
  float* ssb = (float*)alloc(256 * 4);
  float* h2 = h1;
  (void)ws_size; (void)n_in; (void)out_size;

  int egrid = (E + 255) / 256;
  const int GG = 625;  // 625*32 = 20000 exactly

  packw_all<<<1872, 256, 0, stream>>>(bw0, sw0, bw1, sw1, bwo, swo, WPA0, WPA1, WPC,
                                      degE, ssb, partial);
  count_deg<<<egrid, 256, 0, stream>>>(edst, degE, E);
  build_meta2<<<1, 1024, 0, stream>>>(degE, rowptr, cursor, dinv, NN);
  fill_csr<<<egrid, 256, 0, stream>>>(esrc, edst, cursor, csr, E);

  // layer 0 (+ out chunk 0): ssb = identity (written by packw_all)
  gemmSA<<<GG, 768, 0, stream>>>(x, ssb, WPA0, dinv, A, P0);
  aggregate128h<<<5000, 256, 0, stream>>>(A, rowptr, csr, dinv, b0, h1);
  bn_stats<<<625, 256, 0, stream>>>(h1, partial);
  bn_finalB<<<1, 1024, 0, stream>>>(partial, gamma, beta, ssb);

  // layer 1 (+ out chunk 1)
  gemmSA<<<GG, 768, 0, stream>>>(h1, ssb, WPA1, dinv, A, P1);
  aggregate128h<<<5000, 256, 0, stream>>>(A, rowptr, csr, dinv, b1, h2);
  bn_stats<<<625, 256, 0, stream>>>(h2, partial);
  bn_finalB<<<1, 1024, 0, stream>>>(partial, gamma, beta, ssb);

  // out chunk 2 + combine, then aggregate
  gemmSC<<<GG, 512, 0, stream>>>(h2, ssb, WPC, P0, P1, dinv, Ch);
  aggregate40h<<<5000, 256, 0, stream>>>(Ch, rowptr, csr, dinv, bo, (float*)d_out);
}

// Round 21
// 240.123 us; speedup vs baseline: 1.0745x; 1.0538x over previous
//
#include <hip/hip_runtime.h>

#define NN 20000

typedef _Float16 half8 __attribute__((ext_vector_type(8)));
typedef _Float16 half2v __attribute__((ext_vector_type(2)));
typedef float floatx16 __attribute__((ext_vector_type(16)));

#define MFMA32(a, b, c) __builtin_amdgcn_mfma_f32_32x32x16_f16((a), (b), (c), 0, 0, 0)
#define LD8(p) (*(const half8*)(p))

// ---------------- closed-form cubic B-spline basis (knots -2.5+0.5k) ----------------
__device__ __forceinline__ void bspline7_fast(float x, float b[7]) {
  float u = (x + 2.5f) * 2.0f;
  float cf = floorf(u);
  int c = (int)cf;
  float t = u - cf;
  float omt = 1.0f - t;
  float t2 = t * t, t3 = t2 * t;
  float w0 = omt * omt * omt * (1.0f / 6.0f);
  float w1 = (3.0f * t3 - 6.0f * t2 + 4.0f) * (1.0f / 6.0f);
  float w2 = (-3.0f * t3 + 3.0f * t2 + 3.0f * t + 1.0f) * (1.0f / 6.0f);
  float w3 = t3 * (1.0f / 6.0f);
  bool valid = (c >= 0) && (c <= 9);
#pragma unroll
  for (int i = 0; i < 7; ++i) {
    int d = c - i;
    float w = (d == 0) ? w3 : (d == 1) ? w2 : (d == 2) ? w1 : (d == 3) ? w0 : 0.0f;
    b[i] = valid ? w : 0.0f;
  }
}

__device__ __forceinline__ float silu_f(float x) {
  return x * (1.0f / (1.0f + __expf(-x)));
}

__device__ __forceinline__ half8 afrag(float xv) {
  float b[7];
  bspline7_fast(xv, b);
  half8 hv;
  hv[0] = (_Float16)silu_f(xv);
#pragma unroll
  for (int k = 0; k < 7; ++k) hv[k + 1] = (_Float16)b[k];
  return hv;
}

// ---------------- weight packs (32x32x16 B-fragments) + init tail ----------------
__global__ void packw_all(const float* __restrict__ Wb0, const float* __restrict__ Ws0,
                          const float* __restrict__ Wb1, const float* __restrict__ Ws1,
                          const float* __restrict__ WbO, const float* __restrict__ WsO,
                          _Float16* __restrict__ WPA0, _Float16* __restrict__ WPA1,
                          _Float16* __restrict__ WPC, int* __restrict__ degE,
                          float* __restrict__ ssb) {
  int bid = blockIdx.x;
  if (bid < 1536) {
    int s = (bid >= 768) ? 1 : 0;
    int idx = (bid - s * 768) * 256 + threadIdx.x;  // 64*6*64*8 = 196608
    if (idx >= 196608) return;
    const float* Wb = s ? Wb1 : Wb0;
    const float* Wsp = s ? Ws1 : Ws0;
    _Float16* WP = s ? WPA1 : WPA0;
    int j = idx & 7;
    int lane = (idx >> 3) & 63;
    int u = idx >> 9;  // ks*6 + cb32
    int cb = u % 6, ks = u / 6;
    int i = ks * 2 + (lane >> 5);
    int o32 = lane & 31;
    float v = 0.0f;
    if (cb < 4) {
      int o = cb * 32 + o32;
      v = (j == 0) ? Wb[(size_t)o * 128 + i] : Wsp[(size_t)o * 896 + i * 7 + (j - 1)];
    } else {
      int o = (cb - 4) * 32 + o32;
      if (o < 40)
        v = (j == 0) ? WbO[(size_t)o * 384 + s * 128 + i]
                     : WsO[(size_t)o * 2688 + s * 896 + i * 7 + (j - 1)];
    }
    WP[idx] = (_Float16)v;
  } else if (bid < 1792) {
    int idx = (bid - 1536) * 256 + threadIdx.x;  // 64*2*64*8 = 65536
    if (idx >= 65536) return;
    int j = idx & 7;
    int lane = (idx >> 3) & 63;
    int u = idx >> 9;  // ks*2 + cb32
    int cb = u & 1, ks = u >> 1;
    int i = ks * 2 + (lane >> 5);
    int o = cb * 32 + (lane & 31);
    float v = 0.0f;
    if (o < 40)
      v = (j == 0) ? WbO[(size_t)o * 384 + 2 * 128 + i]
                   : WsO[(size_t)o * 2688 + 2 * 896 + i * 7 + (j - 1)];
    WPC[idx] = (_Float16)v;
  } else if (bid < 1871) {
    int idx = (bid - 1792) * 256 + threadIdx.x;
    if (idx < NN) degE[idx] = 0;
  } else {
    int t = threadIdx.x;
    ssb[t] = (t < 128) ? 1.0f : 0.0f;  // identity BN for layer 0
  }
}

// ---------------- graph meta ----------------
__global__ void count_deg(const int* __restrict__ dst, int* __restrict__ degE, int E) {
  int e = blockIdx.x * 256 + threadIdx.x;
  if (e < E) atomicAdd(&degE[dst[e]], 1);
}

__global__ void build_meta2(const int* __restrict__ degE, int* __restrict__ rowptr,
                            int* __restrict__ cursor, float* __restrict__ dinv, int n) {
  __shared__ int wsum[16];
  int tid = threadIdx.x, lane = tid & 63, wid = tid >> 6;
  int i0 = tid * 20;
  int d[20];
  int s = 0;
#pragma unroll
  for (int j = 0; j < 20; ++j) {
    int i = i0 + j;
    int v = (i < n) ? degE[i] : 0;
    d[j] = v;
    s += v;
    if (i < n) dinv[i] = rsqrtf((float)(v + 1));  // +1 self loop
  }
  int val = s;
#pragma unroll
  for (int off = 1; off < 64; off <<= 1) {
    int t = __shfl_up(val, off);
    if (lane >= off) val += t;
  }
  if (lane == 63) wsum[wid] = val;
  __syncthreads();
  if (wid == 0) {
    int wv = (lane < 16) ? wsum[lane] : 0;
#pragma unroll
    for (int off = 1; off < 16; off <<= 1) {
      int t = __shfl_up(wv, off);
      if (lane >= off) wv += t;
    }
    if (lane < 16) wsum[lane] = wv;
  }
  __syncthreads();
  int base = (wid ? wsum[wid - 1] : 0) + val - s;
  if (tid == 0) rowptr[0] = 0;
#pragma unroll
  for (int j = 0; j < 20; ++j) {
    int i = i0 + j;
    if (i < n) {
      cursor[i] = base;
      rowptr[i + 1] = base + d[j];
      base += d[j];
    }
  }
}

__global__ void fill_csr(const int* __restrict__ src, const int* __restrict__ dst,
                         int* __restrict__ cursor, int* __restrict__ csr, int E) {
  int e = blockIdx.x * 256 + threadIdx.x;
  if (e < E) {
    int p = atomicAdd(&cursor[dst[e]], 1);
    csr[p] = src[e];
  }
}

// ---------------- KAN GEMM: fused build + MFMA32 + split-K x2 ----------------
// 768 thr = 12 waves: cb = w%6 (32-col block), kh = w/6 (K half, 32 ks each).
__global__ __launch_bounds__(768) void gemmSA(const float* __restrict__ X,
                                              const float* __restrict__ ss,
                                              const _Float16* __restrict__ WP,
                                              const float* __restrict__ dinv,
                                              _Float16* __restrict__ A, float* __restrict__ P) {
  __shared__ _Float16 Fs[32 * 1024];  // 64 KB
  int tid = threadIdx.x;
  int lane = tid & 63, w = tid >> 6;
  int cb = w % 6, kh = w / 6;
  int row0 = blockIdx.x * 32;
  for (int idx = tid; idx < 4096; idx += 768) {
    int r = idx >> 7, i = idx & 127;
    float xv = X[(size_t)(row0 + r) * 128 + i] * ss[i] + ss[128 + i];
    *(half8*)(Fs + ((size_t)r * 128 + (i ^ (r & 7))) * 8) = afrag(xv);
  }
  __syncthreads();

  int r = lane & 31, hi = lane >> 5, rx = r & 7;
  const _Float16* Fr = Fs + (size_t)r * 1024;
  const _Float16* Bp = WP + ((size_t)cb * 64 + lane) * 8;  // stride 3072 per ks
  floatx16 acc = {};
  int ks0 = kh * 32;
#pragma unroll 4
  for (int ks = ks0; ks < ks0 + 32; ++ks) {
    half8 a = LD8(Fr + (size_t)((2 * ks + hi) ^ rx) * 8);
    half8 b = LD8(Bp + (size_t)ks * 3072);
    acc = MFMA32(a, b, acc);
  }
  __syncthreads();  // all waves done reading Fs
  float* red = (float*)Fs;
  if (kh == 1) {
#pragma unroll
    for (int q = 0; q < 16; ++q) red[q * 384 + cb * 64 + lane] = acc[q];
  }
  __syncthreads();
  if (kh == 0) {
    int col = lane & 31;
#pragma unroll
    for (int q = 0; q < 16; ++q) {
      float v = acc[q] + red[q * 384 + cb * 64 + lane];
      int rl = (q & 3) + 8 * (q >> 2) + 4 * hi;
      if (cb < 4)
        A[(size_t)(row0 + rl) * 128 + cb * 32 + col] = (_Float16)(v * dinv[row0 + rl]);
      else
        P[(size_t)(row0 + rl) * 64 + (cb - 4) * 32 + col] = v;
    }
  }
}

// output chunk 2: fused build + MFMA32 + split-K x4
// 512 thr = 8 waves: cb = w&1, kh = w>>1 (16 ks each).
__global__ __launch_bounds__(512) void gemmSC(const float* __restrict__ X,
                                              const float* __restrict__ ss,
                                              const _Float16* __restrict__ WP,
                                              const float* __restrict__ P0,
                                              const float* __restrict__ P1,
                                              const float* __restrict__ dinv,
                                              _Float16* __restrict__ C) {
  __shared__ _Float16 Fs[32 * 1024];  // 64 KB
  int tid = threadIdx.x;
  int lane = tid & 63, w = tid >> 6;
  int cb = w & 1, kh = w >> 1;
  int row0 = blockIdx.x * 32;
  for (int idx = tid; idx < 4096; idx += 512) {
    int r = idx >> 7, i = idx & 127;
    float xv = X[(size_t)(row0 + r) * 128 + i] * ss[i] + ss[128 + i];
    *(half8*)(Fs + ((size_t)r * 128 + (i ^ (r & 7))) * 8) = afrag(xv);
  }
  __syncthreads();

  int r = lane & 31, hi = lane >> 5, rx = r & 7;
  const _Float16* Fr = Fs + (size_t)r * 1024;
  const _Float16* Bp = WP + ((size_t)cb * 64 + lane) * 8;  // stride 1024 per ks
  floatx16 acc = {};
  int ks0 = kh * 16;
#pragma unroll 4
  for (int ks = ks0; ks < ks0 + 16; ++ks) {
    half8 a = LD8(Fr + (size_t)((2 * ks + hi) ^ rx) * 8);
    half8 b = LD8(Bp + (size_t)ks * 1024);
    acc = MFMA32(a, b, acc);
  }
  __syncthreads();  // all waves done reading Fs
  float* red = (float*)Fs;
  if (kh > 0) {
#pragma unroll
    for (int q = 0; q < 16; ++q)
      red[((kh - 1) * 16 + q) * 128 + cb * 64 + lane] = acc[q];
  }
  __syncthreads();
  if (kh == 0) {
    int col = lane & 31;
#pragma unroll
    for (int q = 0; q < 16; ++q) {
      float v = acc[q] + red[q * 128 + cb * 64 + lane] +
                red[(16 + q) * 128 + cb * 64 + lane] + red[(32 + q) * 128 + cb * 64 + lane];
      int rl = (q & 3) + 8 * (q >> 2) + 4 * hi;
      size_t idx = (size_t)(row0 + rl) * 64 + cb * 32 + col;
      C[idx] = (_Float16)((v + P0[idx] + P1[idx]) * dinv[row0 + rl]);
    }
  }
}

// ---------------- aggregation: wave per node, pre-scaled fp16 rows, 4-way ILP ----------------
__global__ __launch_bounds__(256) void aggregate128h(const _Float16* __restrict__ Ah,
                                                     const int* __restrict__ rowptr,
                                                     const int* __restrict__ csr,
                                                     const float* __restrict__ dinv,
                                                     const float* __restrict__ bias,
                                                     float* __restrict__ Y) {
  int wid = threadIdx.x >> 6, lane = threadIdx.x & 63;
  int n = blockIdx.x * 4 + wid;  // grid 5000 -> n < 20000
  float di = dinv[n];
  half2v self = *(const half2v*)(Ah + (size_t)n * 128 + lane * 2);
  float a0 = (float)self[0], a1 = (float)self[1];
  float b0x = 0, b0y = 0, b1x = 0, b1y = 0, b2x = 0, b2y = 0, b3x = 0, b3y = 0;
  int e0 = rowptr[n], m = rowptr[n + 1] - e0;
  int j = 0;
  for (; j + 4 <= m; j += 4) {
    int s0 = csr[e0 + j], s1 = csr[e0 + j + 1], s2 = csr[e0 + j + 2], s3 = csr[e0 + j + 3];
    half2v r0 = *(const half2v*)(Ah + (size_t)s0 * 128 + lane * 2);
    half2v r1 = *(const half2v*)(Ah + (size_t)s1 * 128 + lane * 2);
    half2v r2 = *(const half2v*)(Ah + (size_t)s2 * 128 + lane * 2);
    half2v r3 = *(const half2v*)(Ah + (size_t)s3 * 128 + lane * 2);
    b0x += (float)r0[0]; b0y += (float)r0[1];
    b1x += (float)r1[0]; b1y += (float)r1[1];
    b2x += (float)r2[0]; b2y += (float)r2[1];
    b3x += (float)r3[0]; b3y += (float)r3[1];
  }
  for (; j < m; ++j) {
    int s = csr[e0 + j];
    half2v rr = *(const half2v*)(Ah + (size_t)s * 128 + lane * 2);
    b0x += (float)rr[0]; b0y += (float)rr[1];
  }
  a0 += (b0x + b1x) + (b2x + b3x);
  a1 += (b0y + b1y) + (b2y + b3y);
  float2 outv = {a0 * di + bias[lane * 2], a1 * di + bias[lane * 2 + 1]};
  *(float2*)(Y + (size_t)n * 128 + lane * 2) = outv;
}

__global__ __launch_bounds__(256) void aggregate40h(const _Float16* __restrict__ Ch,
                                                    const int* __restrict__ rowptr,
                                                    const int* __restrict__ csr,
                                                    const float* __restrict__ dinv,
                                                    const float* __restrict__ bias,
                                                    float* __restrict__ out) {
  int wid = threadIdx.x >> 6, lane = threadIdx.x & 63;
  int n = blockIdx.x * 4 + wid;
  float di = dinv[n];
  float a = (float)Ch[(size_t)n * 64 + lane];
  float b0 = 0, b1 = 0, b2 = 0, b3 = 0;
  int e0 = rowptr[n], m = rowptr[n + 1] - e0;
  int j = 0;
  for (; j + 4 <= m; j += 4) {
    int s0 = csr[e0 + j], s1 = csr[e0 + j + 1], s2 = csr[e0 + j + 2], s3 = csr[e0 + j + 3];
    b0 += (float)Ch[(size_t)s0 * 64 + lane];
    b1 += (float)Ch[(size_t)s1 * 64 + lane];
    b2 += (float)Ch[(size_t)s2 * 64 + lane];
    b3 += (float)Ch[(size_t)s3 * 64 + lane];
  }
  for (; j < m; ++j) {
    int s = csr[e0 + j];
    b0 += (float)Ch[(size_t)s * 64 + lane];
  }
  a += (b0 + b1) + (b2 + b3);
  if (lane < 40) out[(size_t)n * 40 + lane] = a * di + bias[lane];
}

// ---------------- batchnorm: 3-stage deterministic tree ----------------
__global__ __launch_bounds__(256) void bn_stats(const float* __restrict__ H,
                                                float* __restrict__ partial) {
  int tid = threadIdx.x;
  int c4 = (tid & 31) * 4;
  int r0 = blockIdx.x * 32 + (tid >> 5) * 4;
  float s0 = 0, s1 = 0, s2 = 0, s3 = 0, q0 = 0, q1 = 0, q2 = 0, q3 = 0;
#pragma unroll
  for (int j = 0; j < 4; ++j) {
    float4 v = *(const float4*)(H + (size_t)(r0 + j) * 128 + c4);
    s0 += v.x; s1 += v.y; s2 += v.z; s3 += v.w;
    q0 += v.x * v.x; q1 += v.y * v.y; q2 += v.z * v.z; q3 += v.w * v.w;
  }
  __shared__ float sh[2][256][4];
  sh[0][tid][0] = s0; sh[0][tid][1] = s1; sh[0][tid][2] = s2; sh[0][tid][3] = s3;
  sh[1][tid][0] = q0; sh[1][tid][1] = q1; sh[1][tid][2] = q2; sh[1][tid][3] = q3;
  __syncthreads();
  if (tid < 32) {
    float a0 = 0, a1 = 0, a2 = 0, a3 = 0, b0 = 0, b1 = 0, b2 = 0, b3 = 0;
#pragma unroll
    for (int g = 0; g < 8; ++g) {
      int u = g * 32 + tid;
      a0 += sh[0][u][0]; a1 += sh[0][u][1]; a2 += sh[0][u][2]; a3 += sh[0][u][3];
      b0 += sh[1][u][0]; b1 += sh[1][u][1]; b2 += sh[1][u][2]; b3 += sh[1][u][3];
    }
    float* p = partial + (size_t)blockIdx.x * 256;
    p[tid * 4 + 0] = a0; p[tid * 4 + 1] = a1; p[tid * 4 + 2] = a2; p[tid * 4 + 3] = a3;
    p[128 + tid * 4 + 0] = b0; p[128 + tid * 4 + 1] = b1;
    p[128 + tid * 4 + 2] = b2; p[128 + tid * 4 + 3] = b3;
  }
}

__global__ __launch_bounds__(256) void bn_reduce(const float* __restrict__ partial,
                                                 float* __restrict__ p2) {
  int tid = threadIdx.x;
  const float* base = partial + (size_t)blockIdx.x * 25 * 256 + tid;
  float a0 = 0, a1 = 0, a2 = 0, a3 = 0, a4 = 0;
#pragma unroll
  for (int j = 0; j < 5; ++j) {
    a0 += base[(j * 5 + 0) * 256];
    a1 += base[(j * 5 + 1) * 256];
    a2 += base[(j * 5 + 2) * 256];
    a3 += base[(j * 5 + 3) * 256];
    a4 += base[(j * 5 + 4) * 256];
  }
  p2[(size_t)blockIdx.x * 256 + tid] = ((a0 + a1) + (a2 + a3)) + a4;
}

__global__ __launch_bounds__(256) void bn_final2(const float* __restrict__ p2,
                                                 const float* __restrict__ gamma,
                                                 const float* __restrict__ beta,
                                                 float* __restrict__ ss) {
  int tid = threadIdx.x;
  double a0 = 0, a1 = 0, a2 = 0, a3 = 0, a4 = 0;
#pragma unroll
  for (int j = 0; j < 5; ++j) {
    a0 += (double)p2[(size_t)(j * 5 + 0) * 256 + tid];
    a1 += (double)p2[(size_t)(j * 5 + 1) * 256 + tid];
    a2 += (double)p2[(size_t)(j * 5 + 2) * 256 + tid];
    a3 += (double)p2[(size_t)(j * 5 + 3) * 256 + tid];
    a4 += (double)p2[(size_t)(j * 5 + 4) * 256 + tid];
  }
  double tot = ((a0 + a1) + (a2 + a3)) + a4;
  __shared__ double sh[256];
  sh[tid] = tot;
  __syncthreads();
  if (tid < 128) {
    double S = sh[tid];
    double Q = sh[128 + tid];
    double mean = S / (double)NN;
    double var = Q / (double)NN - mean * mean;
    float sc = gamma[tid] * rsqrtf((float)var + 1e-5f);
    ss[tid] = sc;
    ss[128 + tid] = beta[tid] - (float)mean * sc;
  }
}

// ---------------- launch ----------------
extern "C" void kernel_launch(void* const* d_in, const int* in_sizes, int n_in,
                              void* d_out, int out_size, void* d_ws, size_t ws_size,
                              hipStream_t stream) {
  const float* x = (const float*)d_in[0];
  const int* ei = (const int*)d_in[1];
  const float* bw0 = (const float*)d_in[2];
  const float* sw0 = (const float*)d_in[3];
  const float* b0 = (const float*)d_in[4];
  const float* bw1 = (const float*)d_in[5];
  const float* sw1 = (const float*)d_in[6];
  const float* b1 = (const float*)d_in[7];
  const float* bwo = (const float*)d_in[8];
  const float* swo = (const float*)d_in[9];
  const float* bo = (const float*)d_in[10];
  const float* gamma = (const float*)d_in[11];
  const float* beta = (const float*)d_in[12];
  const int E = in_sizes[1] / 2;
  const int* esrc = ei;
  const int* edst = ei + E;

  char* ws = (char*)d_ws;
  size_t off = 0;
  auto alloc = [&](size_t bytes) -> void* {
    void* p = ws + off;
    off = (off + bytes + 255) & ~(size_t)255;
    return p;
  };
  _Float16* WPA0 = (_Float16*)alloc(196608 * 2);
  _Float16* WPA1 = (_Float16*)alloc(196608 * 2);
  _Float16* WPC = (_Float16*)alloc(65536 * 2);
  float* dinv = (float*)alloc(NN * 4);
  int* degE = (int*)alloc(NN * 4);
  int* rowptr = (int*)alloc((NN + 1) * 4);
  int* cursor = (int*)alloc(NN * 4);
  int* csr = (int*)alloc((size_t)E * 4);
  _Float16* A = (_Float16*)alloc((size_t)NN * 128 * 2);  // fp16 pre-scaled GEMM out
  float* h1 = (float*)alloc((size_t)NN * 128 * 4);       // h2 aliases h1
  float* P0 = (float*)alloc((size_t)NN * 64 * 4);
  float* P1 = (float*)alloc((size_t)NN * 64 * 4);
  _Float16* Ch = (_Float16*)alloc((size_t)NN * 64 * 2);
  float* partial = (float*)alloc((size_t)625 * 256 * 4);
  float* p2 = (float*)alloc((size_t)25 * 256 * 4);
  float* ssb = (float*)alloc(256 * 4);
  float* h2 = h1;
  (void)ws_size; (void)n_in; (void)out_size;

  int egrid = (E + 255) / 256;
  const int GG = 625;  // 625*32 = 20000 exactly

  packw_all<<<1872, 256, 0, stream>>>(bw0, sw0, bw1, sw1, bwo, swo, WPA0, WPA1, WPC,
                                      degE, ssb);
  count_deg<<<egrid, 256, 0, stream>>>(edst, degE, E);
  build_meta2<<<1, 1024, 0, stream>>>(degE, rowptr, cursor, dinv, NN);
  fill_csr<<<egrid, 256, 0, stream>>>(esrc, edst, cursor, csr, E);

  // layer 0 (+ out chunk 0): ssb = identity (written by packw_all)
  gemmSA<<<GG, 768, 0, stream>>>(x, ssb, WPA0, dinv, A, P0);
  aggregate128h<<<5000, 256, 0, stream>>>(A, rowptr, csr, dinv, b0, h1);
  bn_stats<<<625, 256, 0, stream>>>(h1, partial);
  bn_reduce<<<25, 256, 0, stream>>>(partial, p2);
  bn_final2<<<1, 256, 0, stream>>>(p2, gamma, beta, ssb);

  // layer 1 (+ out chunk 1)
  gemmSA<<<GG, 768, 0, stream>>>(h1, ssb, WPA1, dinv, A, P1);
  aggregate128h<<<5000, 256, 0, stream>>>(A, rowptr, csr, dinv, b1, h2);
  bn_stats<<<625, 256, 0, stream>>>(h2, partial);
  bn_reduce<<<25, 256, 0, stream>>>(partial, p2);
  bn_final2<<<1, 256, 0, stream>>>(p2, gamma, beta, ssb);

  // out chunk 2 + combine, then aggregate
  gemmSC<<<GG, 512, 0, stream>>>(h2, ssb, WPC, P0, P1, dinv, Ch);
  aggregate40h<<<5000, 256, 0, stream>>>(Ch, rowptr, csr, dinv, bo, (float*)d_out);
}